// Round 14
// baseline (311.493 us; speedup 1.0000x reference)
//
#include <hip/hip_runtime.h>
#include <cstdint>
#include <cstddef>

#define NB    2
#define N1    4096
#define N2    16384
#define CF    64
#define KNN   8
#define SPLIT1 16                 // pass-1 splits
#define NS1   (N1 / SPLIT1)       // 256 candidates per split
#define NQ    (NB * N2)           // 32768 queries

// min/med3 sorted-8 distance network (no index tracking — 8 VALU ops).
#define DNET(d) do { \
    const float m0_ = fminf(d, d0); \
    const float m1_ = __builtin_amdgcn_fmed3f(d, d0, d1); \
    const float m2_ = __builtin_amdgcn_fmed3f(d, d1, d2); \
    const float m3_ = __builtin_amdgcn_fmed3f(d, d2, d3); \
    const float m4_ = __builtin_amdgcn_fmed3f(d, d3, d4); \
    const float m5_ = __builtin_amdgcn_fmed3f(d, d4, d5); \
    const float m6_ = __builtin_amdgcn_fmed3f(d, d5, d6); \
    const float m7_ = __builtin_amdgcn_fmed3f(d, d6, d7); \
    d0=m0_; d1=m1_; d2=m2_; d3=m3_; d4=m4_; d5=m5_; d6=m6_; d7=m7_; \
} while (0)

// exact reference fp32 distance: d = (q2+t2) - (qt+qt), qt=((qx*tx+qy*ty)+qz*tz)
__device__ __forceinline__ float distq(float qx, float qy, float qz, float q2,
                                       float4 p) {
    const float qt = __fadd_rn(
        __fadd_rn(__fmul_rn(qx, p.x), __fmul_rn(qy, p.y)),
        __fmul_rn(qz, p.z));
    return __fsub_rn(__fadd_rn(q2, p.w), __fadd_rn(qt, qt));
}

// ---------------------------------------------------------------------------
// kernel 0: transpose feat1 [B,C,N1] -> feat1T [B,N1,C]; pack xyz1/flow float4
// ---------------------------------------------------------------------------
__global__ __launch_bounds__(256, 2) void k_pack(
    const float* __restrict__ xyz1, const float* __restrict__ feat1,
    const float* __restrict__ flow,
    float* __restrict__ feat1T, float4* __restrict__ aux4,
    float4* __restrict__ flow4)
{
    __shared__ float tile[64][65];
    const int b  = blockIdx.y;
    const int n0 = blockIdx.x * 64;
    const int tid = threadIdx.x;
    const int nl = tid & 63, cq = tid >> 6;

#pragma unroll
    for (int r = 0; r < 16; ++r) {
        const int c = r * 4 + cq;
        tile[c][nl] = feat1[((size_t)(b * CF + c)) * N1 + n0 + nl];
    }
    __syncthreads();
#pragma unroll
    for (int r = 0; r < 16; ++r) {
        const int nn = r * 4 + cq;
        feat1T[((size_t)(b * N1 + n0 + nn)) * CF + nl] = tile[nl][nn];
    }
    if (tid < 64) {
        const int n = n0 + tid;
        const float x = xyz1[(b * 3 + 0) * N1 + n];
        const float y = xyz1[(b * 3 + 1) * N1 + n];
        const float z = xyz1[(b * 3 + 2) * N1 + n];
        aux4[b * N1 + n] = make_float4(x, y, z, 0.f);
        const float fx = flow[(b * 3 + 0) * N1 + n];
        const float fy = flow[(b * 3 + 1) * N1 + n];
        const float fz = flow[(b * 3 + 2) * N1 + n];
        flow4[b * N1 + n] = make_float4(fx, fy, fz, 0.f);
    }
}

// ---------------------------------------------------------------------------
// kernel 1 (R13-proven): per-split 8 smallest DISTANCES. QPT=2.
// ---------------------------------------------------------------------------
__global__ __launch_bounds__(256, 2) void k_knn5(
    const float* __restrict__ xyz1, const float* __restrict__ xyz2,
    float* __restrict__ partd)
{
    __shared__ float4 pts[NS1];  // {x,y,z,t2} — 4 KiB
    const int sp  = blockIdx.y;
    const int tid = threadIdx.x;
    const int qa  = blockIdx.x * 512 + tid;
    const int qb  = qa + 256;
    const int b   = qa >> 14;    // uniform per block (512 | 16384)

    if (tid < NS1) {
        const int jg = sp * NS1 + tid;
        const float x = xyz1[(b * 3 + 0) * N1 + jg];
        const float y = xyz1[(b * 3 + 1) * N1 + jg];
        const float z = xyz1[(b * 3 + 2) * N1 + jg];
        const float t2 = __fadd_rn(__fadd_rn(__fmul_rn(x, x), __fmul_rn(y, y)),
                                   __fmul_rn(z, z));
        pts[tid] = make_float4(x, y, z, t2);
    }
    __syncthreads();

    const int na = qa & (N2 - 1), nb = na + 256;
    const float ax = xyz2[(b * 3 + 0) * N2 + na];
    const float ay = xyz2[(b * 3 + 1) * N2 + na];
    const float az = xyz2[(b * 3 + 2) * N2 + na];
    const float a2 = __fadd_rn(__fadd_rn(__fmul_rn(ax, ax), __fmul_rn(ay, ay)),
                               __fmul_rn(az, az));
    const float cx = xyz2[(b * 3 + 0) * N2 + nb];
    const float cy = xyz2[(b * 3 + 1) * N2 + nb];
    const float cz = xyz2[(b * 3 + 2) * N2 + nb];
    const float c2 = __fadd_rn(__fadd_rn(__fmul_rn(cx, cx), __fmul_rn(cy, cy)),
                               __fmul_rn(cz, cz));

    float Aq0=INFINITY,Aq1=INFINITY,Aq2=INFINITY,Aq3=INFINITY,
          Aq4=INFINITY,Aq5=INFINITY,Aq6=INFINITY,Aq7=INFINITY;
    float Bq0=INFINITY,Bq1=INFINITY,Bq2=INFINITY,Bq3=INFINITY,
          Bq4=INFINITY,Bq5=INFINITY,Bq6=INFINITY,Bq7=INFINITY;

#pragma unroll 4
    for (int j = 0; j < NS1; ++j) {
        const float4 p = pts[j];
        const float dA = distq(ax, ay, az, a2, p);
        const float dB = distq(cx, cy, cz, c2, p);
        {
            float d0=Aq0,d1=Aq1,d2=Aq2,d3=Aq3,d4=Aq4,d5=Aq5,d6=Aq6,d7=Aq7;
            DNET(dA);
            Aq0=d0;Aq1=d1;Aq2=d2;Aq3=d3;Aq4=d4;Aq5=d5;Aq6=d6;Aq7=d7;
        }
        {
            float d0=Bq0,d1=Bq1,d2=Bq2,d3=Bq3,d4=Bq4,d5=Bq5,d6=Bq6,d7=Bq7;
            DNET(dB);
            Bq0=d0;Bq1=d1;Bq2=d2;Bq3=d3;Bq4=d4;Bq5=d5;Bq6=d6;Bq7=d7;
        }
    }

    {
        float* pd = partd + ((size_t)sp * NQ + qa) * KNN;
        pd[0]=Aq0; pd[1]=Aq1; pd[2]=Aq2; pd[3]=Aq3;
        pd[4]=Aq4; pd[5]=Aq5; pd[6]=Aq6; pd[7]=Aq7;
    }
    {
        float* pd = partd + ((size_t)sp * NQ + qb) * KNN;
        pd[0]=Bq0; pd[1]=Bq1; pd[2]=Bq2; pd[3]=Bq3;
        pd[4]=Bq4; pd[5]=Bq5; pd[6]=Bq6; pd[7]=Bq7;
    }
}

// ---------------------------------------------------------------------------
// kernel 2 (R13-proven): merge -> exact global 8th-smallest thr + tneed.
// ---------------------------------------------------------------------------
__global__ __launch_bounds__(256, 2) void k_thr(
    const float* __restrict__ partd, float* __restrict__ thr,
    int* __restrict__ tneed)
{
    const int q = blockIdx.x * 256 + threadIdx.x;
    float d0=INFINITY,d1=INFINITY,d2=INFINITY,d3=INFINITY,
          d4=INFINITY,d5=INFINITY,d6=INFINITY,d7=INFINITY;

#pragma unroll
    for (int sp = 0; sp < SPLIT1; ++sp) {
        const float* pd = partd + ((size_t)sp * NQ + q) * KNN;
#pragma unroll
        for (int r = 0; r < KNN; ++r) {
            const float d = pd[r];
            DNET(d);
        }
    }
    const int s = (d0 < d7) + (d1 < d7) + (d2 < d7) + (d3 < d7) +
                  (d4 < d7) + (d5 < d7) + (d6 < d7);
    thr[q]   = d7;
    tneed[q] = 8 - s;
}

// ---------------------------------------------------------------------------
// kernel 3 (R13-proven): wave-per-query ballot selection, exact threshold.
// ---------------------------------------------------------------------------
__global__ __launch_bounds__(256, 2) void k_sel4(
    const float* __restrict__ xyz1, const float* __restrict__ xyz2,
    const float* __restrict__ thr, const int* __restrict__ tneed,
    int* __restrict__ knn_idx)
{
    __shared__ float4 pts[1024];        // 16 KiB chunk
    const int tid  = threadIdx.x;
    const int wave = tid >> 6, lane = tid & 63;
    const int qbase = blockIdx.x * 8;   // 8 queries per block
    const int b     = qbase >> 14;      // uniform (8 | 16384)

    const int qA = qbase + wave, qB = qA + 4;
    const int nA = qA & (N2 - 1), nB = qB & (N2 - 1);

    const float axA = xyz2[(b * 3 + 0) * N2 + nA];
    const float ayA = xyz2[(b * 3 + 1) * N2 + nA];
    const float azA = xyz2[(b * 3 + 2) * N2 + nA];
    const float a2A = __fadd_rn(__fadd_rn(__fmul_rn(axA, axA), __fmul_rn(ayA, ayA)),
                                __fmul_rn(azA, azA));
    const float axB = xyz2[(b * 3 + 0) * N2 + nB];
    const float ayB = xyz2[(b * 3 + 1) * N2 + nB];
    const float azB = xyz2[(b * 3 + 2) * N2 + nB];
    const float a2B = __fadd_rn(__fadd_rn(__fmul_rn(axB, axB), __fmul_rn(ayB, ayB)),
                                __fmul_rn(azB, azB));

    const float thrA = thr[qA],  thrB = thr[qB];
    const int   tnA  = tneed[qA], tnB = tneed[qB];

    int posA = 0, posB = 0, tcA = 0, tcB = 0;
    int* koA = knn_idx + (size_t)qA * KNN;
    int* koB = knn_idx + (size_t)qB * KNN;

    for (int c = 0; c < 4; ++c) {
        __syncthreads();
        for (int t = tid; t < 1024; t += 256) {
            const int jg = c * 1024 + t;
            const float x = xyz1[(b * 3 + 0) * N1 + jg];
            const float y = xyz1[(b * 3 + 1) * N1 + jg];
            const float z = xyz1[(b * 3 + 2) * N1 + jg];
            const float t2 = __fadd_rn(
                __fadd_rn(__fmul_rn(x, x), __fmul_rn(y, y)), __fmul_rn(z, z));
            pts[t] = make_float4(x, y, z, t2);
        }
        __syncthreads();

        for (int t = 0; t < 16; ++t) {
            const float4 p = pts[t * 64 + lane];
            const float dA = distq(axA, ayA, azA, a2A, p);
            const float dB = distq(axB, ayB, azB, a2B, p);
            unsigned long long sA = __ballot(dA <  thrA);
            unsigned long long eA = __ballot(dA == thrA);
            unsigned long long sB = __ballot(dB <  thrB);
            unsigned long long eB = __ballot(dB == thrB);
            const int jbase = c * 1024 + t * 64;
            while (sA) {
                const int bit = __builtin_ctzll(sA); sA &= sA - 1;
                if (lane == 0 && posA < 8) koA[posA] = jbase + bit;
                ++posA;
            }
            while (eA && tcA < tnA) {
                const int bit = __builtin_ctzll(eA); eA &= eA - 1;
                if (lane == 0 && posA < 8) koA[posA] = jbase + bit;
                ++posA; ++tcA;
            }
            while (sB) {
                const int bit = __builtin_ctzll(sB); sB &= sB - 1;
                if (lane == 0 && posB < 8) koB[posB] = jbase + bit;
                ++posB;
            }
            while (eB && tcB < tnB) {
                const int bit = __builtin_ctzll(eB); eB &= eB - 1;
                if (lane == 0 && posB < 8) koB[posB] = jbase + bit;
                ++posB; ++tcB;
            }
        }
    }
}

// ---------------------------------------------------------------------------
// kernel 4: MLP v6 — NO input LDS. Per-(query,k) input rows are wave-uniform:
// read them via uniform pointers (readfirstlane'd index -> s_load/uniform
// VMEM, one 16B request per wave-instr). Deletes all 136 ds_read_b128/query
// (R13 model: DS pipe = 17.4K ds_reads x 12cyc ~ 87us/CU = the mlp5 wall).
// LDS keeps only the one-time W1 distribution. Math order identical to mlp5
// (c4 ascending per h; dropping fmaf(w,0,h) is bit-exact) -> same absmax.
// ---------------------------------------------------------------------------
#define DPP1(v, CTRL, RM) \
    v += __int_as_float(__builtin_amdgcn_update_dpp( \
        0, __float_as_int(v), CTRL, RM, 0xF, false))

#define DPPALL(CTRL, RM) do { \
    DPP1(pa0,CTRL,RM); DPP1(pb0,CTRL,RM); DPP1(pc0,CTRL,RM); DPP1(pd0,CTRL,RM); \
    DPP1(pa1,CTRL,RM); DPP1(pb1,CTRL,RM); DPP1(pc1,CTRL,RM); DPP1(pd1,CTRL,RM); \
    DPP1(pa2,CTRL,RM); DPP1(pb2,CTRL,RM); DPP1(pc2,CTRL,RM); DPP1(pd2,CTRL,RM); \
} while (0)

#define RDL(v) __int_as_float(__builtin_amdgcn_readlane(__float_as_int(v), 63))

// one c4 round: 8 uniform loads + 32 FMAs (8 independent chains)
#define FMA8(WV, C4) { \
    const float4 f0_ = r0[C4], f1_ = r1[C4], f2_ = r2[C4], f3_ = r3[C4]; \
    const float4 f4_ = r4p[C4], f5_ = r5[C4], f6_ = r6[C4], f7_ = r7[C4]; \
    h0 = fmaf((WV).x, f0_.x, h0); h0 = fmaf((WV).y, f0_.y, h0); \
    h0 = fmaf((WV).z, f0_.z, h0); h0 = fmaf((WV).w, f0_.w, h0); \
    h1 = fmaf((WV).x, f1_.x, h1); h1 = fmaf((WV).y, f1_.y, h1); \
    h1 = fmaf((WV).z, f1_.z, h1); h1 = fmaf((WV).w, f1_.w, h1); \
    h2 = fmaf((WV).x, f2_.x, h2); h2 = fmaf((WV).y, f2_.y, h2); \
    h2 = fmaf((WV).z, f2_.z, h2); h2 = fmaf((WV).w, f2_.w, h2); \
    h3 = fmaf((WV).x, f3_.x, h3); h3 = fmaf((WV).y, f3_.y, h3); \
    h3 = fmaf((WV).z, f3_.z, h3); h3 = fmaf((WV).w, f3_.w, h3); \
    h4 = fmaf((WV).x, f4_.x, h4); h4 = fmaf((WV).y, f4_.y, h4); \
    h4 = fmaf((WV).z, f4_.z, h4); h4 = fmaf((WV).w, f4_.w, h4); \
    h5 = fmaf((WV).x, f5_.x, h5); h5 = fmaf((WV).y, f5_.y, h5); \
    h5 = fmaf((WV).z, f5_.z, h5); h5 = fmaf((WV).w, f5_.w, h5); \
    h6 = fmaf((WV).x, f6_.x, h6); h6 = fmaf((WV).y, f6_.y, h6); \
    h6 = fmaf((WV).z, f6_.z, h6); h6 = fmaf((WV).w, f6_.w, h6); \
    h7 = fmaf((WV).x, f7_.x, h7); h7 = fmaf((WV).y, f7_.y, h7); \
    h7 = fmaf((WV).z, f7_.z, h7); h7 = fmaf((WV).w, f7_.w, h7); \
}

// xyz-diff tail for one h (order matches mlp5's 17th float4: x,y,z; +0 dropped)
#define XYZTAIL(H, IK) { \
    const float4 af_ = aux4[IK]; \
    H = fmaf(w16.x, af_.x - qx, H); \
    H = fmaf(w16.y, af_.y - qy, H); \
    H = fmaf(w16.z, af_.z - qz, H); \
}

// leaky + w2 mul + interleaved DPP reduce for 4 h's (identical to mlp5 quad)
#define L2QUAD(HA, HB, HC, HD, SA0,SA1,SA2,SA3, SB0,SB1,SB2,SB3, SC0,SC1,SC2,SC3) do { \
    float ha = (HA), hb = (HB), hc = (HC), hd = (HD); \
    ha = ha >= 0.f ? ha : 0.1f * ha; \
    hb = hb >= 0.f ? hb : 0.1f * hb; \
    hc = hc >= 0.f ? hc : 0.1f * hc; \
    hd = hd >= 0.f ? hd : 0.1f * hd; \
    float pa0 = w2a*ha, pb0 = w2a*hb, pc0 = w2a*hc, pd0 = w2a*hd; \
    float pa1 = w2b*ha, pb1 = w2b*hb, pc1 = w2b*hc, pd1 = w2b*hd; \
    float pa2 = w2c*ha, pb2 = w2c*hb, pc2 = w2c*hc, pd2 = w2c*hd; \
    DPPALL(0x111, 0xF); DPPALL(0x112, 0xF); DPPALL(0x114, 0xF); \
    DPPALL(0x118, 0xF); DPPALL(0x142, 0xA); DPPALL(0x143, 0xC); \
    SA0 = RDL(pa0) + b20; SA1 = RDL(pb0) + b20; \
    SA2 = RDL(pc0) + b20; SA3 = RDL(pd0) + b20; \
    SB0 = RDL(pa1) + b21; SB1 = RDL(pb1) + b21; \
    SB2 = RDL(pc1) + b21; SB3 = RDL(pd1) + b21; \
    SC0 = RDL(pa2) + b22; SC1 = RDL(pb2) + b22; \
    SC2 = RDL(pc2) + b22; SC3 = RDL(pd2) + b22; \
} while (0)

#define SMAX8F(sa, sb, sc, sd, se, sf, sg, sh, f0,f1,f2,f3,f4,f5,f6,f7, res) do { \
    const float m_ = fmaxf(fmaxf(fmaxf(sa, sb), fmaxf(sc, sd)), \
                           fmaxf(fmaxf(se, sf), fmaxf(sg, sh))); \
    const float e0_ = __expf(sa - m_), e1_ = __expf(sb - m_); \
    const float e2_ = __expf(sc - m_), e3_ = __expf(sd - m_); \
    const float e4_ = __expf(se - m_), e5_ = __expf(sf - m_); \
    const float e6_ = __expf(sg - m_), e7_ = __expf(sh - m_); \
    const float S_ = ((e0_ + e1_) + (e2_ + e3_)) + ((e4_ + e5_) + (e6_ + e7_)); \
    float acc_ = e0_ * (f0); \
    acc_ = fmaf(e1_, (f1), acc_); acc_ = fmaf(e2_, (f2), acc_); \
    acc_ = fmaf(e3_, (f3), acc_); acc_ = fmaf(e4_, (f4), acc_); \
    acc_ = fmaf(e5_, (f5), acc_); acc_ = fmaf(e6_, (f6), acc_); \
    acc_ = fmaf(e7_, (f7), acc_); \
    res = acc_ / S_; \
} while (0)

__global__ __launch_bounds__(256, 2) void k_mlp6(
    const float* __restrict__ feat1T, const float4* __restrict__ aux4,
    const float4* __restrict__ flow4, const int* __restrict__ knn_idx,
    const float* __restrict__ xyz2,
    const float* __restrict__ W1, const float* __restrict__ b1,
    const float* __restrict__ W2, const float* __restrict__ b2,
    float* __restrict__ out)
{
    __shared__ __align__(16) float w1s[64 * 68];   // only LDS: weight distribution

    const int tid  = threadIdx.x;
    const int wave = tid >> 6, lane = tid & 63;

    for (int t = tid; t < 64 * 67; t += 256) {
        const int o = t / 67, c = t - o * 67;
        w1s[o * 68 + c] = W1[t];
    }
    if (tid < 64) w1s[tid * 68 + 67] = 0.f;

    const float b1v = b1[lane];
    const float w2a = W2[lane], w2b = W2[64 + lane], w2c = W2[128 + lane];
    const float b20 = b2[0], b21 = b2[1], b22 = b2[2];
    __syncthreads();   // the only cross-wave barrier

    const float4* wr = (const float4*)&w1s[lane * 68];
    const float4 w0 = wr[0],  w1 = wr[1],  w2 = wr[2],  w3 = wr[3];
    const float4 w4 = wr[4],  w5 = wr[5],  w6 = wr[6],  w7 = wr[7];
    const float4 w8 = wr[8],  w9 = wr[9],  w10 = wr[10], w11 = wr[11];
    const float4 w12 = wr[12], w13 = wr[13], w14 = wr[14], w15 = wr[15];
    const float4 w16 = wr[16];

    const int q0   = blockIdx.x * 32 + wave * 8;   // 8 queries per wave
    const int b    = q0 >> 14;                      // uniform (32 | 16384)
    const int base = b * N1;
    const int n0   = q0 & (N2 - 1);

#pragma unroll
    for (int it = 0; it < 8; ++it) {
        const int q = q0 + it;
        const int n = n0 + it;
        const int* kq = knn_idx + (size_t)q * KNN;

        const float qx = xyz2[(b * 3 + 0) * N2 + n];
        const float qy = xyz2[(b * 3 + 1) * N2 + n];
        const float qz = xyz2[(b * 3 + 2) * N2 + n];

        // wave-uniform neighbor indices -> uniform row pointers
        const int i0 = __builtin_amdgcn_readfirstlane(base + kq[0]);
        const int i1 = __builtin_amdgcn_readfirstlane(base + kq[1]);
        const int i2 = __builtin_amdgcn_readfirstlane(base + kq[2]);
        const int i3 = __builtin_amdgcn_readfirstlane(base + kq[3]);
        const int i4 = __builtin_amdgcn_readfirstlane(base + kq[4]);
        const int i5 = __builtin_amdgcn_readfirstlane(base + kq[5]);
        const int i6 = __builtin_amdgcn_readfirstlane(base + kq[6]);
        const int i7 = __builtin_amdgcn_readfirstlane(base + kq[7]);
        const float4* r0  = (const float4*)(feat1T + (size_t)i0 * CF);
        const float4* r1  = (const float4*)(feat1T + (size_t)i1 * CF);
        const float4* r2  = (const float4*)(feat1T + (size_t)i2 * CF);
        const float4* r3  = (const float4*)(feat1T + (size_t)i3 * CF);
        const float4* r4p = (const float4*)(feat1T + (size_t)i4 * CF);
        const float4* r5  = (const float4*)(feat1T + (size_t)i5 * CF);
        const float4* r6  = (const float4*)(feat1T + (size_t)i6 * CF);
        const float4* r7  = (const float4*)(feat1T + (size_t)i7 * CF);

        // layer 1: c4-outer / kk-inner (8 independent chains, 8 loads/round)
        float h0 = b1v, h1 = b1v, h2 = b1v, h3 = b1v;
        float h4 = b1v, h5 = b1v, h6 = b1v, h7 = b1v;
        FMA8(w0, 0)  FMA8(w1, 1)  FMA8(w2, 2)  FMA8(w3, 3)
        FMA8(w4, 4)  FMA8(w5, 5)  FMA8(w6, 6)  FMA8(w7, 7)
        FMA8(w8, 8)  FMA8(w9, 9)  FMA8(w10,10) FMA8(w11,11)
        FMA8(w12,12) FMA8(w13,13) FMA8(w14,14) FMA8(w15,15)
        XYZTAIL(h0, i0) XYZTAIL(h1, i1) XYZTAIL(h2, i2) XYZTAIL(h3, i3)
        XYZTAIL(h4, i4) XYZTAIL(h5, i5) XYZTAIL(h6, i6) XYZTAIL(h7, i7)

        // flow vectors (wave-uniform loads), needed for softmax
        const float4 fl0 = flow4[i0], fl1 = flow4[i1];
        const float4 fl2 = flow4[i2], fl3 = flow4[i3];
        const float4 fl4 = flow4[i4], fl5 = flow4[i5];
        const float4 fl6 = flow4[i6], fl7 = flow4[i7];

        // layer 2 (DPP wave reductions, 12 chains interleaved per quad)
        float s00, s01, s02, s03, s04, s05, s06, s07;
        float s10, s11, s12, s13, s14, s15, s16, s17;
        float s20, s21, s22, s23, s24, s25, s26, s27;
        L2QUAD(h0, h1, h2, h3, s00,s01,s02,s03, s10,s11,s12,s13, s20,s21,s22,s23);
        L2QUAD(h4, h5, h6, h7, s04,s05,s06,s07, s14,s15,s16,s17, s24,s25,s26,s27);

        float res0, res1, res2;
        SMAX8F(s00,s01,s02,s03,s04,s05,s06,s07,
               fl0.x,fl1.x,fl2.x,fl3.x,fl4.x,fl5.x,fl6.x,fl7.x, res0);
        SMAX8F(s10,s11,s12,s13,s14,s15,s16,s17,
               fl0.y,fl1.y,fl2.y,fl3.y,fl4.y,fl5.y,fl6.y,fl7.y, res1);
        SMAX8F(s20,s21,s22,s23,s24,s25,s26,s27,
               fl0.z,fl1.z,fl2.z,fl3.z,fl4.z,fl5.z,fl6.z,fl7.z, res2);

        const float resv = lane == 0 ? res0 : (lane == 1 ? res1 : res2);
        if (lane < 3) out[((size_t)(b * 3 + lane)) * N2 + n] = resv;
    }
}

// ---------------------------------------------------------------------------
extern "C" void kernel_launch(void* const* d_in, const int* in_sizes, int n_in,
                              void* d_out, int out_size, void* d_ws, size_t ws_size,
                              hipStream_t stream)
{
    const float* xyz1  = (const float*)d_in[0];
    const float* xyz2  = (const float*)d_in[1];
    const float* feat1 = (const float*)d_in[2];
    const float* flow  = (const float*)d_in[3];
    const float* W1    = (const float*)d_in[4];
    const float* b1    = (const float*)d_in[5];
    const float* W2    = (const float*)d_in[6];
    const float* b2    = (const float*)d_in[7];
    float* out = (float*)d_out;

    // ws layout: feat1T 2M @0 | aux4 .5M @2M | flow4 .5M @2.5M |
    //            knn_idx 1M @3M | partd 16M @4M | thr .5M @20M |
    //            tneed .5M @20.5M   (21 MiB total; 35.25 proven in R9)
    char* ws = (char*)d_ws;
    float*  feat1T  = (float*)(ws);
    float4* aux4    = (float4*)(ws + (size_t)(2u << 20));
    float4* flow4   = (float4*)(ws + (size_t)(2u << 20) + (512u << 10));
    int*    knn_idx = (int*)  (ws + (size_t)(3u << 20));
    float*  partd   = (float*)(ws + (size_t)(4u << 20));
    float*  thr     = (float*)(ws + (size_t)(20u << 20));
    int*    tneed   = (int*)  (ws + (size_t)(20u << 20) + (512u << 10));

    hipLaunchKernelGGL(k_pack, dim3(N1 / 64, NB), dim3(256), 0, stream,
                       xyz1, feat1, flow, feat1T, aux4, flow4);
    hipLaunchKernelGGL(k_knn5, dim3(NQ / 512, SPLIT1), dim3(256), 0, stream,
                       xyz1, xyz2, partd);
    hipLaunchKernelGGL(k_thr, dim3(NQ / 256), dim3(256), 0, stream,
                       partd, thr, tneed);
    hipLaunchKernelGGL(k_sel4, dim3(NQ / 8), dim3(256), 0, stream,
                       xyz1, xyz2, thr, tneed, knn_idx);
    hipLaunchKernelGGL(k_mlp6, dim3(NQ / 32), dim3(256), 0, stream,
                       feat1T, aux4, flow4, knn_idx, xyz2, W1, b1, W2, b2, out);
}

// Round 15
// 295.709 us; speedup vs baseline: 1.0534x; 1.0534x over previous
//
#include <hip/hip_runtime.h>
#include <cstdint>
#include <cstddef>

#define NB    2
#define N1    4096
#define N2    16384
#define CF    64
#define KNN   8
#define SPLIT1 16                 // pass-1 splits
#define NS1   (N1 / SPLIT1)       // 256 candidates per split
#define NQ    (NB * N2)           // 32768 queries

// min/med3 sorted-8 distance network (no index tracking — 8 VALU ops).
#define DNET(d) do { \
    const float m0_ = fminf(d, d0); \
    const float m1_ = __builtin_amdgcn_fmed3f(d, d0, d1); \
    const float m2_ = __builtin_amdgcn_fmed3f(d, d1, d2); \
    const float m3_ = __builtin_amdgcn_fmed3f(d, d2, d3); \
    const float m4_ = __builtin_amdgcn_fmed3f(d, d3, d4); \
    const float m5_ = __builtin_amdgcn_fmed3f(d, d4, d5); \
    const float m6_ = __builtin_amdgcn_fmed3f(d, d5, d6); \
    const float m7_ = __builtin_amdgcn_fmed3f(d, d6, d7); \
    d0=m0_; d1=m1_; d2=m2_; d3=m3_; d4=m4_; d5=m5_; d6=m6_; d7=m7_; \
} while (0)

// exact reference fp32 distance: d = (q2+t2) - (qt+qt), qt=((qx*tx+qy*ty)+qz*tz)
__device__ __forceinline__ float distq(float qx, float qy, float qz, float q2,
                                       float4 p) {
    const float qt = __fadd_rn(
        __fadd_rn(__fmul_rn(qx, p.x), __fmul_rn(qy, p.y)),
        __fmul_rn(qz, p.z));
    return __fsub_rn(__fadd_rn(q2, p.w), __fadd_rn(qt, qt));
}

// ---------------------------------------------------------------------------
// kernel 0: transpose feat1 [B,C,N1] -> feat1T [B,N1,C]; pack xyz1/flow float4
// ---------------------------------------------------------------------------
__global__ __launch_bounds__(256, 2) void k_pack(
    const float* __restrict__ xyz1, const float* __restrict__ feat1,
    const float* __restrict__ flow,
    float* __restrict__ feat1T, float4* __restrict__ aux4,
    float4* __restrict__ flow4)
{
    __shared__ float tile[64][65];
    const int b  = blockIdx.y;
    const int n0 = blockIdx.x * 64;
    const int tid = threadIdx.x;
    const int nl = tid & 63, cq = tid >> 6;

#pragma unroll
    for (int r = 0; r < 16; ++r) {
        const int c = r * 4 + cq;
        tile[c][nl] = feat1[((size_t)(b * CF + c)) * N1 + n0 + nl];
    }
    __syncthreads();
#pragma unroll
    for (int r = 0; r < 16; ++r) {
        const int nn = r * 4 + cq;
        feat1T[((size_t)(b * N1 + n0 + nn)) * CF + nl] = tile[nl][nn];
    }
    if (tid < 64) {
        const int n = n0 + tid;
        const float x = xyz1[(b * 3 + 0) * N1 + n];
        const float y = xyz1[(b * 3 + 1) * N1 + n];
        const float z = xyz1[(b * 3 + 2) * N1 + n];
        aux4[b * N1 + n] = make_float4(x, y, z, 0.f);
        const float fx = flow[(b * 3 + 0) * N1 + n];
        const float fy = flow[(b * 3 + 1) * N1 + n];
        const float fz = flow[(b * 3 + 2) * N1 + n];
        flow4[b * N1 + n] = make_float4(fx, fy, fz, 0.f);
    }
}

// ---------------------------------------------------------------------------
// kernel 1 (R13-proven): per-split 8 smallest DISTANCES. QPT=2.
// ---------------------------------------------------------------------------
__global__ __launch_bounds__(256, 2) void k_knn5(
    const float* __restrict__ xyz1, const float* __restrict__ xyz2,
    float* __restrict__ partd)
{
    __shared__ float4 pts[NS1];  // {x,y,z,t2} — 4 KiB
    const int sp  = blockIdx.y;
    const int tid = threadIdx.x;
    const int qa  = blockIdx.x * 512 + tid;
    const int qb  = qa + 256;
    const int b   = qa >> 14;    // uniform per block (512 | 16384)

    if (tid < NS1) {
        const int jg = sp * NS1 + tid;
        const float x = xyz1[(b * 3 + 0) * N1 + jg];
        const float y = xyz1[(b * 3 + 1) * N1 + jg];
        const float z = xyz1[(b * 3 + 2) * N1 + jg];
        const float t2 = __fadd_rn(__fadd_rn(__fmul_rn(x, x), __fmul_rn(y, y)),
                                   __fmul_rn(z, z));
        pts[tid] = make_float4(x, y, z, t2);
    }
    __syncthreads();

    const int na = qa & (N2 - 1), nb = na + 256;
    const float ax = xyz2[(b * 3 + 0) * N2 + na];
    const float ay = xyz2[(b * 3 + 1) * N2 + na];
    const float az = xyz2[(b * 3 + 2) * N2 + na];
    const float a2 = __fadd_rn(__fadd_rn(__fmul_rn(ax, ax), __fmul_rn(ay, ay)),
                               __fmul_rn(az, az));
    const float cx = xyz2[(b * 3 + 0) * N2 + nb];
    const float cy = xyz2[(b * 3 + 1) * N2 + nb];
    const float cz = xyz2[(b * 3 + 2) * N2 + nb];
    const float c2 = __fadd_rn(__fadd_rn(__fmul_rn(cx, cx), __fmul_rn(cy, cy)),
                               __fmul_rn(cz, cz));

    float Aq0=INFINITY,Aq1=INFINITY,Aq2=INFINITY,Aq3=INFINITY,
          Aq4=INFINITY,Aq5=INFINITY,Aq6=INFINITY,Aq7=INFINITY;
    float Bq0=INFINITY,Bq1=INFINITY,Bq2=INFINITY,Bq3=INFINITY,
          Bq4=INFINITY,Bq5=INFINITY,Bq6=INFINITY,Bq7=INFINITY;

#pragma unroll 4
    for (int j = 0; j < NS1; ++j) {
        const float4 p = pts[j];
        const float dA = distq(ax, ay, az, a2, p);
        const float dB = distq(cx, cy, cz, c2, p);
        {
            float d0=Aq0,d1=Aq1,d2=Aq2,d3=Aq3,d4=Aq4,d5=Aq5,d6=Aq6,d7=Aq7;
            DNET(dA);
            Aq0=d0;Aq1=d1;Aq2=d2;Aq3=d3;Aq4=d4;Aq5=d5;Aq6=d6;Aq7=d7;
        }
        {
            float d0=Bq0,d1=Bq1,d2=Bq2,d3=Bq3,d4=Bq4,d5=Bq5,d6=Bq6,d7=Bq7;
            DNET(dB);
            Bq0=d0;Bq1=d1;Bq2=d2;Bq3=d3;Bq4=d4;Bq5=d5;Bq6=d6;Bq7=d7;
        }
    }

    {
        float* pd = partd + ((size_t)sp * NQ + qa) * KNN;
        pd[0]=Aq0; pd[1]=Aq1; pd[2]=Aq2; pd[3]=Aq3;
        pd[4]=Aq4; pd[5]=Aq5; pd[6]=Aq6; pd[7]=Aq7;
    }
    {
        float* pd = partd + ((size_t)sp * NQ + qb) * KNN;
        pd[0]=Bq0; pd[1]=Bq1; pd[2]=Bq2; pd[3]=Bq3;
        pd[4]=Bq4; pd[5]=Bq5; pd[6]=Bq6; pd[7]=Bq7;
    }
}

// ---------------------------------------------------------------------------
// kernel 2 (R13-proven): merge -> exact global 8th-smallest thr + tneed.
// ---------------------------------------------------------------------------
__global__ __launch_bounds__(256, 2) void k_thr(
    const float* __restrict__ partd, float* __restrict__ thr,
    int* __restrict__ tneed)
{
    const int q = blockIdx.x * 256 + threadIdx.x;
    float d0=INFINITY,d1=INFINITY,d2=INFINITY,d3=INFINITY,
          d4=INFINITY,d5=INFINITY,d6=INFINITY,d7=INFINITY;

#pragma unroll
    for (int sp = 0; sp < SPLIT1; ++sp) {
        const float* pd = partd + ((size_t)sp * NQ + q) * KNN;
#pragma unroll
        for (int r = 0; r < KNN; ++r) {
            const float d = pd[r];
            DNET(d);
        }
    }
    const int s = (d0 < d7) + (d1 < d7) + (d2 < d7) + (d3 < d7) +
                  (d4 < d7) + (d5 < d7) + (d6 < d7);
    thr[q]   = d7;
    tneed[q] = 8 - s;
}

// ---------------------------------------------------------------------------
// kernel 3: wave-per-query ballot selection, exact threshold (R13-proven
// logic) — now 16 queries/block (4 per wave) to halve the pts staging
// traffic and barrier count (R14: 4096 blocks re-staged 64KB each for only
// 8 queries). Extraction loops stay wave-uniform SALU.
// ---------------------------------------------------------------------------
__global__ __launch_bounds__(256, 2) void k_sel4(
    const float* __restrict__ xyz1, const float* __restrict__ xyz2,
    const float* __restrict__ thr, const int* __restrict__ tneed,
    int* __restrict__ knn_idx)
{
    __shared__ float4 pts[1024];        // 16 KiB chunk
    const int tid  = threadIdx.x;
    const int wave = tid >> 6, lane = tid & 63;
    const int qbase = blockIdx.x * 16;  // 16 queries per block
    const int b     = qbase >> 14;      // uniform (16 | 16384)

    const int qA = qbase + wave,  qB = qA + 4;
    const int qC = qA + 8,        qD = qA + 12;
    const int nA = qA & (N2 - 1), nB = qB & (N2 - 1);
    const int nC = qC & (N2 - 1), nD = qD & (N2 - 1);

    const float axA = xyz2[(b * 3 + 0) * N2 + nA];
    const float ayA = xyz2[(b * 3 + 1) * N2 + nA];
    const float azA = xyz2[(b * 3 + 2) * N2 + nA];
    const float a2A = __fadd_rn(__fadd_rn(__fmul_rn(axA, axA), __fmul_rn(ayA, ayA)),
                                __fmul_rn(azA, azA));
    const float axB = xyz2[(b * 3 + 0) * N2 + nB];
    const float ayB = xyz2[(b * 3 + 1) * N2 + nB];
    const float azB = xyz2[(b * 3 + 2) * N2 + nB];
    const float a2B = __fadd_rn(__fadd_rn(__fmul_rn(axB, axB), __fmul_rn(ayB, ayB)),
                                __fmul_rn(azB, azB));
    const float axC = xyz2[(b * 3 + 0) * N2 + nC];
    const float ayC = xyz2[(b * 3 + 1) * N2 + nC];
    const float azC = xyz2[(b * 3 + 2) * N2 + nC];
    const float a2C = __fadd_rn(__fadd_rn(__fmul_rn(axC, axC), __fmul_rn(ayC, ayC)),
                                __fmul_rn(azC, azC));
    const float axD = xyz2[(b * 3 + 0) * N2 + nD];
    const float ayD = xyz2[(b * 3 + 1) * N2 + nD];
    const float azD = xyz2[(b * 3 + 2) * N2 + nD];
    const float a2D = __fadd_rn(__fadd_rn(__fmul_rn(axD, axD), __fmul_rn(ayD, ayD)),
                                __fmul_rn(azD, azD));

    const float thrA = thr[qA], thrB = thr[qB], thrC = thr[qC], thrD = thr[qD];
    const int   tnA = tneed[qA], tnB = tneed[qB];
    const int   tnC = tneed[qC], tnD = tneed[qD];

    int posA = 0, posB = 0, posC = 0, posD = 0;
    int tcA = 0, tcB = 0, tcC = 0, tcD = 0;
    int* koA = knn_idx + (size_t)qA * KNN;
    int* koB = knn_idx + (size_t)qB * KNN;
    int* koC = knn_idx + (size_t)qC * KNN;
    int* koD = knn_idx + (size_t)qD * KNN;

    for (int c = 0; c < 4; ++c) {
        __syncthreads();   // WAR: previous chunk fully consumed
        for (int t = tid; t < 1024; t += 256) {
            const int jg = c * 1024 + t;
            const float x = xyz1[(b * 3 + 0) * N1 + jg];
            const float y = xyz1[(b * 3 + 1) * N1 + jg];
            const float z = xyz1[(b * 3 + 2) * N1 + jg];
            const float t2 = __fadd_rn(
                __fadd_rn(__fmul_rn(x, x), __fmul_rn(y, y)), __fmul_rn(z, z));
            pts[t] = make_float4(x, y, z, t2);
        }
        __syncthreads();

        for (int t = 0; t < 16; ++t) {
            const float4 p = pts[t * 64 + lane];
            const float dA = distq(axA, ayA, azA, a2A, p);
            const float dB = distq(axB, ayB, azB, a2B, p);
            const float dC = distq(axC, ayC, azC, a2C, p);
            const float dD = distq(axD, ayD, azD, a2D, p);
            unsigned long long sA = __ballot(dA <  thrA);
            unsigned long long eA = __ballot(dA == thrA);
            unsigned long long sB = __ballot(dB <  thrB);
            unsigned long long eB = __ballot(dB == thrB);
            unsigned long long sC = __ballot(dC <  thrC);
            unsigned long long eC = __ballot(dC == thrC);
            unsigned long long sD = __ballot(dD <  thrD);
            unsigned long long eD = __ballot(dD == thrD);
            const int jbase = c * 1024 + t * 64;
            while (sA) {
                const int bit = __builtin_ctzll(sA); sA &= sA - 1;
                if (lane == 0 && posA < 8) koA[posA] = jbase + bit;
                ++posA;
            }
            while (eA && tcA < tnA) {
                const int bit = __builtin_ctzll(eA); eA &= eA - 1;
                if (lane == 0 && posA < 8) koA[posA] = jbase + bit;
                ++posA; ++tcA;
            }
            while (sB) {
                const int bit = __builtin_ctzll(sB); sB &= sB - 1;
                if (lane == 0 && posB < 8) koB[posB] = jbase + bit;
                ++posB;
            }
            while (eB && tcB < tnB) {
                const int bit = __builtin_ctzll(eB); eB &= eB - 1;
                if (lane == 0 && posB < 8) koB[posB] = jbase + bit;
                ++posB; ++tcB;
            }
            while (sC) {
                const int bit = __builtin_ctzll(sC); sC &= sC - 1;
                if (lane == 0 && posC < 8) koC[posC] = jbase + bit;
                ++posC;
            }
            while (eC && tcC < tnC) {
                const int bit = __builtin_ctzll(eC); eC &= eC - 1;
                if (lane == 0 && posC < 8) koC[posC] = jbase + bit;
                ++posC; ++tcC;
            }
            while (sD) {
                const int bit = __builtin_ctzll(sD); sD &= sD - 1;
                if (lane == 0 && posD < 8) koD[posD] = jbase + bit;
                ++posD;
            }
            while (eD && tcD < tnD) {
                const int bit = __builtin_ctzll(eD); eD &= eD - 1;
                if (lane == 0 && posD < 8) koD[posD] = jbase + bit;
                ++posD; ++tcD;
            }
        }
    }
}

// ---------------------------------------------------------------------------
// kernel 4: MLP v5 — EXACT R13 version (116.4 us proven; mlp6's uniform-VMEM
// variant regressed to 127 us, VALUBusy 39% = latency-bound). 4 waves share
// w1s, quad-ILP layer 1, interleaved DPP reductions, QPW=8.
// ---------------------------------------------------------------------------
#define R4(WV, C4, BK) { \
    const float4 i0_ = *(const float4*)(inw + ((BK)+0)*68 + (C4)*4); \
    const float4 i1_ = *(const float4*)(inw + ((BK)+1)*68 + (C4)*4); \
    const float4 i2_ = *(const float4*)(inw + ((BK)+2)*68 + (C4)*4); \
    const float4 i3_ = *(const float4*)(inw + ((BK)+3)*68 + (C4)*4); \
    ha = fmaf((WV).x, i0_.x, ha); ha = fmaf((WV).y, i0_.y, ha); \
    ha = fmaf((WV).z, i0_.z, ha); ha = fmaf((WV).w, i0_.w, ha); \
    hb = fmaf((WV).x, i1_.x, hb); hb = fmaf((WV).y, i1_.y, hb); \
    hb = fmaf((WV).z, i1_.z, hb); hb = fmaf((WV).w, i1_.w, hb); \
    hc = fmaf((WV).x, i2_.x, hc); hc = fmaf((WV).y, i2_.y, hc); \
    hc = fmaf((WV).z, i2_.z, hc); hc = fmaf((WV).w, i2_.w, hc); \
    hd = fmaf((WV).x, i3_.x, hd); hd = fmaf((WV).y, i3_.y, hd); \
    hd = fmaf((WV).z, i3_.z, hd); hd = fmaf((WV).w, i3_.w, hd); \
}

#define DPP1(v, CTRL, RM) \
    v += __int_as_float(__builtin_amdgcn_update_dpp( \
        0, __float_as_int(v), CTRL, RM, 0xF, false))

#define DPPALL(CTRL, RM) do { \
    DPP1(pa0,CTRL,RM); DPP1(pb0,CTRL,RM); DPP1(pc0,CTRL,RM); DPP1(pd0,CTRL,RM); \
    DPP1(pa1,CTRL,RM); DPP1(pb1,CTRL,RM); DPP1(pc1,CTRL,RM); DPP1(pd1,CTRL,RM); \
    DPP1(pa2,CTRL,RM); DPP1(pb2,CTRL,RM); DPP1(pc2,CTRL,RM); DPP1(pd2,CTRL,RM); \
} while (0)

#define RDL(v) __int_as_float(__builtin_amdgcn_readlane(__float_as_int(v), 63))

#define L1L2_QUAD(BK, SA0,SA1,SA2,SA3, SB0,SB1,SB2,SB3, SC0,SC1,SC2,SC3) do { \
    float ha = b1v, hb = b1v, hc = b1v, hd = b1v; \
    R4(w0, 0, BK)  R4(w1, 1, BK)  R4(w2, 2, BK)  R4(w3, 3, BK) \
    R4(w4, 4, BK)  R4(w5, 5, BK)  R4(w6, 6, BK)  R4(w7, 7, BK) \
    R4(w8, 8, BK)  R4(w9, 9, BK)  R4(w10,10, BK) R4(w11,11, BK) \
    R4(w12,12, BK) R4(w13,13, BK) R4(w14,14, BK) R4(w15,15, BK) \
    R4(w16,16, BK) \
    ha = ha >= 0.f ? ha : 0.1f * ha; \
    hb = hb >= 0.f ? hb : 0.1f * hb; \
    hc = hc >= 0.f ? hc : 0.1f * hc; \
    hd = hd >= 0.f ? hd : 0.1f * hd; \
    float pa0 = w2a*ha, pb0 = w2a*hb, pc0 = w2a*hc, pd0 = w2a*hd; \
    float pa1 = w2b*ha, pb1 = w2b*hb, pc1 = w2b*hc, pd1 = w2b*hd; \
    float pa2 = w2c*ha, pb2 = w2c*hb, pc2 = w2c*hc, pd2 = w2c*hd; \
    DPPALL(0x111, 0xF); DPPALL(0x112, 0xF); DPPALL(0x114, 0xF); \
    DPPALL(0x118, 0xF); DPPALL(0x142, 0xA); DPPALL(0x143, 0xC); \
    SA0 = RDL(pa0) + b20; SA1 = RDL(pb0) + b20; \
    SA2 = RDL(pc0) + b20; SA3 = RDL(pd0) + b20; \
    SB0 = RDL(pa1) + b21; SB1 = RDL(pb1) + b21; \
    SB2 = RDL(pc1) + b21; SB3 = RDL(pd1) + b21; \
    SC0 = RDL(pa2) + b22; SC1 = RDL(pb2) + b22; \
    SC2 = RDL(pc2) + b22; SC3 = RDL(pd2) + b22; \
} while (0)

#define SMAX8(sa, sb, sc, sd, se, sf, sg, sh, CH, res) do { \
    const float m_ = fmaxf(fmaxf(fmaxf(sa, sb), fmaxf(sc, sd)), \
                           fmaxf(fmaxf(se, sf), fmaxf(sg, sh))); \
    const float e0_ = __expf(sa - m_), e1_ = __expf(sb - m_); \
    const float e2_ = __expf(sc - m_), e3_ = __expf(sd - m_); \
    const float e4_ = __expf(se - m_), e5_ = __expf(sf - m_); \
    const float e6_ = __expf(sg - m_), e7_ = __expf(sh - m_); \
    const float S_ = ((e0_ + e1_) + (e2_ + e3_)) + ((e4_ + e5_) + (e6_ + e7_)); \
    float acc_ = e0_ * flf[0 * 4 + CH]; \
    acc_ = fmaf(e1_, flf[1 * 4 + CH], acc_); acc_ = fmaf(e2_, flf[2 * 4 + CH], acc_); \
    acc_ = fmaf(e3_, flf[3 * 4 + CH], acc_); acc_ = fmaf(e4_, flf[4 * 4 + CH], acc_); \
    acc_ = fmaf(e5_, flf[5 * 4 + CH], acc_); acc_ = fmaf(e6_, flf[6 * 4 + CH], acc_); \
    acc_ = fmaf(e7_, flf[7 * 4 + CH], acc_); \
    res = acc_ / S_; \
} while (0)

#define MLP_STEP(IT) do { \
    const int n_ = n0 + (IT); \
    __builtin_amdgcn_wave_barrier(); \
    float4* drow = (float4*)(inw + k * 68); \
    drow[p * 2] = g0; drow[p * 2 + 1] = g1; \
    if (p == 0) { \
        inw[k * 68 + 64] = axv.x - qx; inw[k * 68 + 65] = axv.y - qy; \
        inw[k * 68 + 66] = axv.z - qz; inw[k * 68 + 67] = 0.f; \
    } \
    if (p == 1) flbuf[wave][k] = flv; \
    __builtin_amdgcn_wave_barrier(); \
    if ((IT) < 7) { \
        const int idn_ = idnext; \
        const float4* fr_ = (const float4*)(feat1T + (size_t)(base + idn_) * CF); \
        g0 = fr_[p * 2]; g1 = fr_[p * 2 + 1]; \
        axv = aux4[base + idn_]; flv = flow4[base + idn_]; \
        qx = xyz2[(b * 3 + 0) * N2 + n_ + 1]; \
        qy = xyz2[(b * 3 + 1) * N2 + n_ + 1]; \
        qz = xyz2[(b * 3 + 2) * N2 + n_ + 1]; \
        if ((IT) < 6) idnext = knn_idx[(size_t)(q0 + (IT) + 2) * KNN + k]; \
    } \
    float s00, s01, s02, s03, s04, s05, s06, s07; \
    float s10, s11, s12, s13, s14, s15, s16, s17; \
    float s20, s21, s22, s23, s24, s25, s26, s27; \
    L1L2_QUAD(0, s00,s01,s02,s03, s10,s11,s12,s13, s20,s21,s22,s23); \
    L1L2_QUAD(4, s04,s05,s06,s07, s14,s15,s16,s17, s24,s25,s26,s27); \
    float res0, res1, res2; \
    SMAX8(s00, s01, s02, s03, s04, s05, s06, s07, 0, res0); \
    SMAX8(s10, s11, s12, s13, s14, s15, s16, s17, 1, res1); \
    SMAX8(s20, s21, s22, s23, s24, s25, s26, s27, 2, res2); \
    const float resv = lane == 0 ? res0 : (lane == 1 ? res1 : res2); \
    if (lane < 3) out[((size_t)(b * 3 + lane)) * N2 + n_] = resv; \
} while (0)

__global__ __launch_bounds__(256, 2) void k_mlp5(
    const float* __restrict__ feat1T, const float4* __restrict__ aux4,
    const float4* __restrict__ flow4, const int* __restrict__ knn_idx,
    const float* __restrict__ xyz2,
    const float* __restrict__ W1, const float* __restrict__ b1,
    const float* __restrict__ W2, const float* __restrict__ b2,
    float* __restrict__ out)
{
    __shared__ __align__(16) float w1s[64 * 68];
    __shared__ __align__(16) float inbuf[4][8][68];
    __shared__ __align__(16) float4 flbuf[4][8];

    const int tid  = threadIdx.x;
    const int wave = tid >> 6, lane = tid & 63;

    for (int t = tid; t < 64 * 67; t += 256) {
        const int o = t / 67, c = t - o * 67;
        w1s[o * 68 + c] = W1[t];
    }
    if (tid < 64) w1s[tid * 68 + 67] = 0.f;

    const float b1v = b1[lane];
    const float w2a = W2[lane], w2b = W2[64 + lane], w2c = W2[128 + lane];
    const float b20 = b2[0], b21 = b2[1], b22 = b2[2];
    __syncthreads();

    const float4* wr = (const float4*)&w1s[lane * 68];
    const float4 w0 = wr[0],  w1 = wr[1],  w2 = wr[2],  w3 = wr[3];
    const float4 w4 = wr[4],  w5 = wr[5],  w6 = wr[6],  w7 = wr[7];
    const float4 w8 = wr[8],  w9 = wr[9],  w10 = wr[10], w11 = wr[11];
    const float4 w12 = wr[12], w13 = wr[13], w14 = wr[14], w15 = wr[15];
    const float4 w16 = wr[16];

    const int k = lane >> 3, p = lane & 7;
    float* inw = &inbuf[wave][0][0];
    const float* flf = (const float*)&flbuf[wave][0];

    const int q0   = blockIdx.x * 32 + wave * 8;
    const int b    = q0 >> 14;
    const int base = b * N1;
    const int n0   = q0 & (N2 - 1);

    const int id0v = knn_idx[(size_t)q0 * KNN + k];
    int idnext     = knn_idx[(size_t)(q0 + 1) * KNN + k];

    const float4* fr0 = (const float4*)(feat1T + (size_t)(base + id0v) * CF);
    float4 g0 = fr0[p * 2], g1 = fr0[p * 2 + 1];
    float4 axv = aux4[base + id0v];
    float4 flv = flow4[base + id0v];
    float qx = xyz2[(b * 3 + 0) * N2 + n0];
    float qy = xyz2[(b * 3 + 1) * N2 + n0];
    float qz = xyz2[(b * 3 + 2) * N2 + n0];

    MLP_STEP(0);
    MLP_STEP(1);
    MLP_STEP(2);
    MLP_STEP(3);
    MLP_STEP(4);
    MLP_STEP(5);
    MLP_STEP(6);
    MLP_STEP(7);
}

// ---------------------------------------------------------------------------
extern "C" void kernel_launch(void* const* d_in, const int* in_sizes, int n_in,
                              void* d_out, int out_size, void* d_ws, size_t ws_size,
                              hipStream_t stream)
{
    const float* xyz1  = (const float*)d_in[0];
    const float* xyz2  = (const float*)d_in[1];
    const float* feat1 = (const float*)d_in[2];
    const float* flow  = (const float*)d_in[3];
    const float* W1    = (const float*)d_in[4];
    const float* b1    = (const float*)d_in[5];
    const float* W2    = (const float*)d_in[6];
    const float* b2    = (const float*)d_in[7];
    float* out = (float*)d_out;

    // ws layout: feat1T 2M @0 | aux4 .5M @2M | flow4 .5M @2.5M |
    //            knn_idx 1M @3M | partd 16M @4M | thr .5M @20M |
    //            tneed .5M @20.5M   (21 MiB total; 35.25 proven in R9)
    char* ws = (char*)d_ws;
    float*  feat1T  = (float*)(ws);
    float4* aux4    = (float4*)(ws + (size_t)(2u << 20));
    float4* flow4   = (float4*)(ws + (size_t)(2u << 20) + (512u << 10));
    int*    knn_idx = (int*)  (ws + (size_t)(3u << 20));
    float*  partd   = (float*)(ws + (size_t)(4u << 20));
    float*  thr     = (float*)(ws + (size_t)(20u << 20));
    int*    tneed   = (int*)  (ws + (size_t)(20u << 20) + (512u << 10));

    hipLaunchKernelGGL(k_pack, dim3(N1 / 64, NB), dim3(256), 0, stream,
                       xyz1, feat1, flow, feat1T, aux4, flow4);
    hipLaunchKernelGGL(k_knn5, dim3(NQ / 512, SPLIT1), dim3(256), 0, stream,
                       xyz1, xyz2, partd);
    hipLaunchKernelGGL(k_thr, dim3(NQ / 256), dim3(256), 0, stream,
                       partd, thr, tneed);
    hipLaunchKernelGGL(k_sel4, dim3(NQ / 16), dim3(256), 0, stream,
                       xyz1, xyz2, thr, tneed, knn_idx);
    hipLaunchKernelGGL(k_mlp5, dim3(NQ / 32), dim3(256), 0, stream,
                       feat1T, aux4, flow4, knn_idx, xyz2, W1, b1, W2, b2, out);
}

// Round 16
// 290.941 us; speedup vs baseline: 1.0706x; 1.0164x over previous
//
#include <hip/hip_runtime.h>
#include <cstdint>
#include <cstddef>

#define NB    2
#define N1    4096
#define N2    16384
#define CF    64
#define KNN   8
#define SPLIT1 16                 // pass-1 splits
#define NS1   (N1 / SPLIT1)       // 256 candidates per split
#define NQ    (NB * N2)           // 32768 queries

// min/med3 sorted-8 distance network (no index tracking — 8 VALU ops).
#define DNET(d) do { \
    const float m0_ = fminf(d, d0); \
    const float m1_ = __builtin_amdgcn_fmed3f(d, d0, d1); \
    const float m2_ = __builtin_amdgcn_fmed3f(d, d1, d2); \
    const float m3_ = __builtin_amdgcn_fmed3f(d, d2, d3); \
    const float m4_ = __builtin_amdgcn_fmed3f(d, d3, d4); \
    const float m5_ = __builtin_amdgcn_fmed3f(d, d4, d5); \
    const float m6_ = __builtin_amdgcn_fmed3f(d, d5, d6); \
    const float m7_ = __builtin_amdgcn_fmed3f(d, d6, d7); \
    d0=m0_; d1=m1_; d2=m2_; d3=m3_; d4=m4_; d5=m5_; d6=m6_; d7=m7_; \
} while (0)

// exact reference fp32 distance: d = (q2+t2) - (qt+qt), qt=((qx*tx+qy*ty)+qz*tz)
__device__ __forceinline__ float distq(float qx, float qy, float qz, float q2,
                                       float4 p) {
    const float qt = __fadd_rn(
        __fadd_rn(__fmul_rn(qx, p.x), __fmul_rn(qy, p.y)),
        __fmul_rn(qz, p.z));
    return __fsub_rn(__fadd_rn(q2, p.w), __fadd_rn(qt, qt));
}

// ---------------------------------------------------------------------------
// kernel 0: transpose feat1 [B,C,N1] -> feat1T [B,N1,C]; pack xyz1/flow float4
// ---------------------------------------------------------------------------
__global__ __launch_bounds__(256, 2) void k_pack(
    const float* __restrict__ xyz1, const float* __restrict__ feat1,
    const float* __restrict__ flow,
    float* __restrict__ feat1T, float4* __restrict__ aux4,
    float4* __restrict__ flow4)
{
    __shared__ float tile[64][65];
    const int b  = blockIdx.y;
    const int n0 = blockIdx.x * 64;
    const int tid = threadIdx.x;
    const int nl = tid & 63, cq = tid >> 6;

#pragma unroll
    for (int r = 0; r < 16; ++r) {
        const int c = r * 4 + cq;
        tile[c][nl] = feat1[((size_t)(b * CF + c)) * N1 + n0 + nl];
    }
    __syncthreads();
#pragma unroll
    for (int r = 0; r < 16; ++r) {
        const int nn = r * 4 + cq;
        feat1T[((size_t)(b * N1 + n0 + nn)) * CF + nl] = tile[nl][nn];
    }
    if (tid < 64) {
        const int n = n0 + tid;
        const float x = xyz1[(b * 3 + 0) * N1 + n];
        const float y = xyz1[(b * 3 + 1) * N1 + n];
        const float z = xyz1[(b * 3 + 2) * N1 + n];
        aux4[b * N1 + n] = make_float4(x, y, z, 0.f);
        const float fx = flow[(b * 3 + 0) * N1 + n];
        const float fy = flow[(b * 3 + 1) * N1 + n];
        const float fz = flow[(b * 3 + 2) * N1 + n];
        flow4[b * N1 + n] = make_float4(fx, fy, fz, 0.f);
    }
}

// ---------------------------------------------------------------------------
// kernel 1 (R13-proven math): per-split 8 smallest DISTANCES. QPT=2.
// launch_bounds(256,4): knn5 needs ~45 VGPRs << 128 cap — no spill risk —
// and raises the residency floor to 4 waves/EU for extra latency hiding.
// ---------------------------------------------------------------------------
__global__ __launch_bounds__(256, 4) void k_knn5(
    const float* __restrict__ xyz1, const float* __restrict__ xyz2,
    float* __restrict__ partd)
{
    __shared__ float4 pts[NS1];  // {x,y,z,t2} — 4 KiB
    const int sp  = blockIdx.y;
    const int tid = threadIdx.x;
    const int qa  = blockIdx.x * 512 + tid;
    const int qb  = qa + 256;
    const int b   = qa >> 14;    // uniform per block (512 | 16384)

    if (tid < NS1) {
        const int jg = sp * NS1 + tid;
        const float x = xyz1[(b * 3 + 0) * N1 + jg];
        const float y = xyz1[(b * 3 + 1) * N1 + jg];
        const float z = xyz1[(b * 3 + 2) * N1 + jg];
        const float t2 = __fadd_rn(__fadd_rn(__fmul_rn(x, x), __fmul_rn(y, y)),
                                   __fmul_rn(z, z));
        pts[tid] = make_float4(x, y, z, t2);
    }
    __syncthreads();

    const int na = qa & (N2 - 1), nb = na + 256;
    const float ax = xyz2[(b * 3 + 0) * N2 + na];
    const float ay = xyz2[(b * 3 + 1) * N2 + na];
    const float az = xyz2[(b * 3 + 2) * N2 + na];
    const float a2 = __fadd_rn(__fadd_rn(__fmul_rn(ax, ax), __fmul_rn(ay, ay)),
                               __fmul_rn(az, az));
    const float cx = xyz2[(b * 3 + 0) * N2 + nb];
    const float cy = xyz2[(b * 3 + 1) * N2 + nb];
    const float cz = xyz2[(b * 3 + 2) * N2 + nb];
    const float c2 = __fadd_rn(__fadd_rn(__fmul_rn(cx, cx), __fmul_rn(cy, cy)),
                               __fmul_rn(cz, cz));

    float Aq0=INFINITY,Aq1=INFINITY,Aq2=INFINITY,Aq3=INFINITY,
          Aq4=INFINITY,Aq5=INFINITY,Aq6=INFINITY,Aq7=INFINITY;
    float Bq0=INFINITY,Bq1=INFINITY,Bq2=INFINITY,Bq3=INFINITY,
          Bq4=INFINITY,Bq5=INFINITY,Bq6=INFINITY,Bq7=INFINITY;

#pragma unroll 4
    for (int j = 0; j < NS1; ++j) {
        const float4 p = pts[j];
        const float dA = distq(ax, ay, az, a2, p);
        const float dB = distq(cx, cy, cz, c2, p);
        {
            float d0=Aq0,d1=Aq1,d2=Aq2,d3=Aq3,d4=Aq4,d5=Aq5,d6=Aq6,d7=Aq7;
            DNET(dA);
            Aq0=d0;Aq1=d1;Aq2=d2;Aq3=d3;Aq4=d4;Aq5=d5;Aq6=d6;Aq7=d7;
        }
        {
            float d0=Bq0,d1=Bq1,d2=Bq2,d3=Bq3,d4=Bq4,d5=Bq5,d6=Bq6,d7=Bq7;
            DNET(dB);
            Bq0=d0;Bq1=d1;Bq2=d2;Bq3=d3;Bq4=d4;Bq5=d5;Bq6=d6;Bq7=d7;
        }
    }

    {
        float* pd = partd + ((size_t)sp * NQ + qa) * KNN;
        pd[0]=Aq0; pd[1]=Aq1; pd[2]=Aq2; pd[3]=Aq3;
        pd[4]=Aq4; pd[5]=Aq5; pd[6]=Aq6; pd[7]=Aq7;
    }
    {
        float* pd = partd + ((size_t)sp * NQ + qb) * KNN;
        pd[0]=Bq0; pd[1]=Bq1; pd[2]=Bq2; pd[3]=Bq3;
        pd[4]=Bq4; pd[5]=Bq5; pd[6]=Bq6; pd[7]=Bq7;
    }
}

// ---------------------------------------------------------------------------
// kernel 2 (R13-proven): merge -> exact global 8th-smallest thr + tneed.
// ---------------------------------------------------------------------------
__global__ __launch_bounds__(256, 2) void k_thr(
    const float* __restrict__ partd, float* __restrict__ thr,
    int* __restrict__ tneed)
{
    const int q = blockIdx.x * 256 + threadIdx.x;
    float d0=INFINITY,d1=INFINITY,d2=INFINITY,d3=INFINITY,
          d4=INFINITY,d5=INFINITY,d6=INFINITY,d7=INFINITY;

#pragma unroll
    for (int sp = 0; sp < SPLIT1; ++sp) {
        const float* pd = partd + ((size_t)sp * NQ + q) * KNN;
#pragma unroll
        for (int r = 0; r < KNN; ++r) {
            const float d = pd[r];
            DNET(d);
        }
    }
    const int s = (d0 < d7) + (d1 < d7) + (d2 < d7) + (d3 < d7) +
                  (d4 < d7) + (d5 < d7) + (d6 < d7);
    thr[q]   = d7;
    tneed[q] = 8 - s;
}

// ---------------------------------------------------------------------------
// kernel 3 (R13-proven, 8 q/block — the 16 q/block variant of R15 regressed
// ~4.5 us): wave-per-query ballot selection with EXACT threshold. Strict hits
// (d < thr) all accepted (<= 7 total); ties (d == thr) accepted while
// tcnt < tneed in ascending-index order. Total accepted = exactly 8.
// Extraction loops are wave-uniform SALU (ctz) — no per-lane carried chains.
// ---------------------------------------------------------------------------
__global__ __launch_bounds__(256, 2) void k_sel4(
    const float* __restrict__ xyz1, const float* __restrict__ xyz2,
    const float* __restrict__ thr, const int* __restrict__ tneed,
    int* __restrict__ knn_idx)
{
    __shared__ float4 pts[1024];        // 16 KiB chunk
    const int tid  = threadIdx.x;
    const int wave = tid >> 6, lane = tid & 63;
    const int qbase = blockIdx.x * 8;   // 8 queries per block
    const int b     = qbase >> 14;      // uniform (8 | 16384)

    const int qA = qbase + wave, qB = qA + 4;
    const int nA = qA & (N2 - 1), nB = qB & (N2 - 1);

    const float axA = xyz2[(b * 3 + 0) * N2 + nA];
    const float ayA = xyz2[(b * 3 + 1) * N2 + nA];
    const float azA = xyz2[(b * 3 + 2) * N2 + nA];
    const float a2A = __fadd_rn(__fadd_rn(__fmul_rn(axA, axA), __fmul_rn(ayA, ayA)),
                                __fmul_rn(azA, azA));
    const float axB = xyz2[(b * 3 + 0) * N2 + nB];
    const float ayB = xyz2[(b * 3 + 1) * N2 + nB];
    const float azB = xyz2[(b * 3 + 2) * N2 + nB];
    const float a2B = __fadd_rn(__fadd_rn(__fmul_rn(axB, axB), __fmul_rn(ayB, ayB)),
                                __fmul_rn(azB, azB));

    const float thrA = thr[qA],  thrB = thr[qB];
    const int   tnA  = tneed[qA], tnB = tneed[qB];

    int posA = 0, posB = 0, tcA = 0, tcB = 0;
    int* koA = knn_idx + (size_t)qA * KNN;
    int* koB = knn_idx + (size_t)qB * KNN;

    for (int c = 0; c < 4; ++c) {
        __syncthreads();
        for (int t = tid; t < 1024; t += 256) {
            const int jg = c * 1024 + t;
            const float x = xyz1[(b * 3 + 0) * N1 + jg];
            const float y = xyz1[(b * 3 + 1) * N1 + jg];
            const float z = xyz1[(b * 3 + 2) * N1 + jg];
            const float t2 = __fadd_rn(
                __fadd_rn(__fmul_rn(x, x), __fmul_rn(y, y)), __fmul_rn(z, z));
            pts[t] = make_float4(x, y, z, t2);
        }
        __syncthreads();

        for (int t = 0; t < 16; ++t) {
            const float4 p = pts[t * 64 + lane];
            const float dA = distq(axA, ayA, azA, a2A, p);
            const float dB = distq(axB, ayB, azB, a2B, p);
            unsigned long long sA = __ballot(dA <  thrA);
            unsigned long long eA = __ballot(dA == thrA);
            unsigned long long sB = __ballot(dB <  thrB);
            unsigned long long eB = __ballot(dB == thrB);
            const int jbase = c * 1024 + t * 64;
            while (sA) {
                const int bit = __builtin_ctzll(sA); sA &= sA - 1;
                if (lane == 0 && posA < 8) koA[posA] = jbase + bit;
                ++posA;
            }
            while (eA && tcA < tnA) {
                const int bit = __builtin_ctzll(eA); eA &= eA - 1;
                if (lane == 0 && posA < 8) koA[posA] = jbase + bit;
                ++posA; ++tcA;
            }
            while (sB) {
                const int bit = __builtin_ctzll(sB); sB &= sB - 1;
                if (lane == 0 && posB < 8) koB[posB] = jbase + bit;
                ++posB;
            }
            while (eB && tcB < tnB) {
                const int bit = __builtin_ctzll(eB); eB &= eB - 1;
                if (lane == 0 && posB < 8) koB[posB] = jbase + bit;
                ++posB; ++tcB;
            }
        }
    }
}

// ---------------------------------------------------------------------------
// kernel 4: MLP v5 — EXACT R13/R15 version (115-116 us proven best).
// ---------------------------------------------------------------------------
#define R4(WV, C4, BK) { \
    const float4 i0_ = *(const float4*)(inw + ((BK)+0)*68 + (C4)*4); \
    const float4 i1_ = *(const float4*)(inw + ((BK)+1)*68 + (C4)*4); \
    const float4 i2_ = *(const float4*)(inw + ((BK)+2)*68 + (C4)*4); \
    const float4 i3_ = *(const float4*)(inw + ((BK)+3)*68 + (C4)*4); \
    ha = fmaf((WV).x, i0_.x, ha); ha = fmaf((WV).y, i0_.y, ha); \
    ha = fmaf((WV).z, i0_.z, ha); ha = fmaf((WV).w, i0_.w, ha); \
    hb = fmaf((WV).x, i1_.x, hb); hb = fmaf((WV).y, i1_.y, hb); \
    hb = fmaf((WV).z, i1_.z, hb); hb = fmaf((WV).w, i1_.w, hb); \
    hc = fmaf((WV).x, i2_.x, hc); hc = fmaf((WV).y, i2_.y, hc); \
    hc = fmaf((WV).z, i2_.z, hc); hc = fmaf((WV).w, i2_.w, hc); \
    hd = fmaf((WV).x, i3_.x, hd); hd = fmaf((WV).y, i3_.y, hd); \
    hd = fmaf((WV).z, i3_.z, hd); hd = fmaf((WV).w, i3_.w, hd); \
}

#define DPP1(v, CTRL, RM) \
    v += __int_as_float(__builtin_amdgcn_update_dpp( \
        0, __float_as_int(v), CTRL, RM, 0xF, false))

#define DPPALL(CTRL, RM) do { \
    DPP1(pa0,CTRL,RM); DPP1(pb0,CTRL,RM); DPP1(pc0,CTRL,RM); DPP1(pd0,CTRL,RM); \
    DPP1(pa1,CTRL,RM); DPP1(pb1,CTRL,RM); DPP1(pc1,CTRL,RM); DPP1(pd1,CTRL,RM); \
    DPP1(pa2,CTRL,RM); DPP1(pb2,CTRL,RM); DPP1(pc2,CTRL,RM); DPP1(pd2,CTRL,RM); \
} while (0)

#define RDL(v) __int_as_float(__builtin_amdgcn_readlane(__float_as_int(v), 63))

#define L1L2_QUAD(BK, SA0,SA1,SA2,SA3, SB0,SB1,SB2,SB3, SC0,SC1,SC2,SC3) do { \
    float ha = b1v, hb = b1v, hc = b1v, hd = b1v; \
    R4(w0, 0, BK)  R4(w1, 1, BK)  R4(w2, 2, BK)  R4(w3, 3, BK) \
    R4(w4, 4, BK)  R4(w5, 5, BK)  R4(w6, 6, BK)  R4(w7, 7, BK) \
    R4(w8, 8, BK)  R4(w9, 9, BK)  R4(w10,10, BK) R4(w11,11, BK) \
    R4(w12,12, BK) R4(w13,13, BK) R4(w14,14, BK) R4(w15,15, BK) \
    R4(w16,16, BK) \
    ha = ha >= 0.f ? ha : 0.1f * ha; \
    hb = hb >= 0.f ? hb : 0.1f * hb; \
    hc = hc >= 0.f ? hc : 0.1f * hc; \
    hd = hd >= 0.f ? hd : 0.1f * hd; \
    float pa0 = w2a*ha, pb0 = w2a*hb, pc0 = w2a*hc, pd0 = w2a*hd; \
    float pa1 = w2b*ha, pb1 = w2b*hb, pc1 = w2b*hc, pd1 = w2b*hd; \
    float pa2 = w2c*ha, pb2 = w2c*hb, pc2 = w2c*hc, pd2 = w2c*hd; \
    DPPALL(0x111, 0xF); DPPALL(0x112, 0xF); DPPALL(0x114, 0xF); \
    DPPALL(0x118, 0xF); DPPALL(0x142, 0xA); DPPALL(0x143, 0xC); \
    SA0 = RDL(pa0) + b20; SA1 = RDL(pb0) + b20; \
    SA2 = RDL(pc0) + b20; SA3 = RDL(pd0) + b20; \
    SB0 = RDL(pa1) + b21; SB1 = RDL(pb1) + b21; \
    SB2 = RDL(pc1) + b21; SB3 = RDL(pd1) + b21; \
    SC0 = RDL(pa2) + b22; SC1 = RDL(pb2) + b22; \
    SC2 = RDL(pc2) + b22; SC3 = RDL(pd2) + b22; \
} while (0)

#define SMAX8(sa, sb, sc, sd, se, sf, sg, sh, CH, res) do { \
    const float m_ = fmaxf(fmaxf(fmaxf(sa, sb), fmaxf(sc, sd)), \
                           fmaxf(fmaxf(se, sf), fmaxf(sg, sh))); \
    const float e0_ = __expf(sa - m_), e1_ = __expf(sb - m_); \
    const float e2_ = __expf(sc - m_), e3_ = __expf(sd - m_); \
    const float e4_ = __expf(se - m_), e5_ = __expf(sf - m_); \
    const float e6_ = __expf(sg - m_), e7_ = __expf(sh - m_); \
    const float S_ = ((e0_ + e1_) + (e2_ + e3_)) + ((e4_ + e5_) + (e6_ + e7_)); \
    float acc_ = e0_ * flf[0 * 4 + CH]; \
    acc_ = fmaf(e1_, flf[1 * 4 + CH], acc_); acc_ = fmaf(e2_, flf[2 * 4 + CH], acc_); \
    acc_ = fmaf(e3_, flf[3 * 4 + CH], acc_); acc_ = fmaf(e4_, flf[4 * 4 + CH], acc_); \
    acc_ = fmaf(e5_, flf[5 * 4 + CH], acc_); acc_ = fmaf(e6_, flf[6 * 4 + CH], acc_); \
    acc_ = fmaf(e7_, flf[7 * 4 + CH], acc_); \
    res = acc_ / S_; \
} while (0)

#define MLP_STEP(IT) do { \
    const int n_ = n0 + (IT); \
    __builtin_amdgcn_wave_barrier(); \
    float4* drow = (float4*)(inw + k * 68); \
    drow[p * 2] = g0; drow[p * 2 + 1] = g1; \
    if (p == 0) { \
        inw[k * 68 + 64] = axv.x - qx; inw[k * 68 + 65] = axv.y - qy; \
        inw[k * 68 + 66] = axv.z - qz; inw[k * 68 + 67] = 0.f; \
    } \
    if (p == 1) flbuf[wave][k] = flv; \
    __builtin_amdgcn_wave_barrier(); \
    if ((IT) < 7) { \
        const int idn_ = idnext; \
        const float4* fr_ = (const float4*)(feat1T + (size_t)(base + idn_) * CF); \
        g0 = fr_[p * 2]; g1 = fr_[p * 2 + 1]; \
        axv = aux4[base + idn_]; flv = flow4[base + idn_]; \
        qx = xyz2[(b * 3 + 0) * N2 + n_ + 1]; \
        qy = xyz2[(b * 3 + 1) * N2 + n_ + 1]; \
        qz = xyz2[(b * 3 + 2) * N2 + n_ + 1]; \
        if ((IT) < 6) idnext = knn_idx[(size_t)(q0 + (IT) + 2) * KNN + k]; \
    } \
    float s00, s01, s02, s03, s04, s05, s06, s07; \
    float s10, s11, s12, s13, s14, s15, s16, s17; \
    float s20, s21, s22, s23, s24, s25, s26, s27; \
    L1L2_QUAD(0, s00,s01,s02,s03, s10,s11,s12,s13, s20,s21,s22,s23); \
    L1L2_QUAD(4, s04,s05,s06,s07, s14,s15,s16,s17, s24,s25,s26,s27); \
    float res0, res1, res2; \
    SMAX8(s00, s01, s02, s03, s04, s05, s06, s07, 0, res0); \
    SMAX8(s10, s11, s12, s13, s14, s15, s16, s17, 1, res1); \
    SMAX8(s20, s21, s22, s23, s24, s25, s26, s27, 2, res2); \
    const float resv = lane == 0 ? res0 : (lane == 1 ? res1 : res2); \
    if (lane < 3) out[((size_t)(b * 3 + lane)) * N2 + n_] = resv; \
} while (0)

__global__ __launch_bounds__(256, 2) void k_mlp5(
    const float* __restrict__ feat1T, const float4* __restrict__ aux4,
    const float4* __restrict__ flow4, const int* __restrict__ knn_idx,
    const float* __restrict__ xyz2,
    const float* __restrict__ W1, const float* __restrict__ b1,
    const float* __restrict__ W2, const float* __restrict__ b2,
    float* __restrict__ out)
{
    __shared__ __align__(16) float w1s[64 * 68];
    __shared__ __align__(16) float inbuf[4][8][68];
    __shared__ __align__(16) float4 flbuf[4][8];

    const int tid  = threadIdx.x;
    const int wave = tid >> 6, lane = tid & 63;

    for (int t = tid; t < 64 * 67; t += 256) {
        const int o = t / 67, c = t - o * 67;
        w1s[o * 68 + c] = W1[t];
    }
    if (tid < 64) w1s[tid * 68 + 67] = 0.f;

    const float b1v = b1[lane];
    const float w2a = W2[lane], w2b = W2[64 + lane], w2c = W2[128 + lane];
    const float b20 = b2[0], b21 = b2[1], b22 = b2[2];
    __syncthreads();

    const float4* wr = (const float4*)&w1s[lane * 68];
    const float4 w0 = wr[0],  w1 = wr[1],  w2 = wr[2],  w3 = wr[3];
    const float4 w4 = wr[4],  w5 = wr[5],  w6 = wr[6],  w7 = wr[7];
    const float4 w8 = wr[8],  w9 = wr[9],  w10 = wr[10], w11 = wr[11];
    const float4 w12 = wr[12], w13 = wr[13], w14 = wr[14], w15 = wr[15];
    const float4 w16 = wr[16];

    const int k = lane >> 3, p = lane & 7;
    float* inw = &inbuf[wave][0][0];
    const float* flf = (const float*)&flbuf[wave][0];

    const int q0   = blockIdx.x * 32 + wave * 8;
    const int b    = q0 >> 14;
    const int base = b * N1;
    const int n0   = q0 & (N2 - 1);

    const int id0v = knn_idx[(size_t)q0 * KNN + k];
    int idnext     = knn_idx[(size_t)(q0 + 1) * KNN + k];

    const float4* fr0 = (const float4*)(feat1T + (size_t)(base + id0v) * CF);
    float4 g0 = fr0[p * 2], g1 = fr0[p * 2 + 1];
    float4 axv = aux4[base + id0v];
    float4 flv = flow4[base + id0v];
    float qx = xyz2[(b * 3 + 0) * N2 + n0];
    float qy = xyz2[(b * 3 + 1) * N2 + n0];
    float qz = xyz2[(b * 3 + 2) * N2 + n0];

    MLP_STEP(0);
    MLP_STEP(1);
    MLP_STEP(2);
    MLP_STEP(3);
    MLP_STEP(4);
    MLP_STEP(5);
    MLP_STEP(6);
    MLP_STEP(7);
}

// ---------------------------------------------------------------------------
extern "C" void kernel_launch(void* const* d_in, const int* in_sizes, int n_in,
                              void* d_out, int out_size, void* d_ws, size_t ws_size,
                              hipStream_t stream)
{
    const float* xyz1  = (const float*)d_in[0];
    const float* xyz2  = (const float*)d_in[1];
    const float* feat1 = (const float*)d_in[2];
    const float* flow  = (const float*)d_in[3];
    const float* W1    = (const float*)d_in[4];
    const float* b1    = (const float*)d_in[5];
    const float* W2    = (const float*)d_in[6];
    const float* b2    = (const float*)d_in[7];
    float* out = (float*)d_out;

    // ws layout: feat1T 2M @0 | aux4 .5M @2M | flow4 .5M @2.5M |
    //            knn_idx 1M @3M | partd 16M @4M | thr .5M @20M |
    //            tneed .5M @20.5M   (21 MiB total; 35.25 proven in R9)
    char* ws = (char*)d_ws;
    float*  feat1T  = (float*)(ws);
    float4* aux4    = (float4*)(ws + (size_t)(2u << 20));
    float4* flow4   = (float4*)(ws + (size_t)(2u << 20) + (512u << 10));
    int*    knn_idx = (int*)  (ws + (size_t)(3u << 20));
    float*  partd   = (float*)(ws + (size_t)(4u << 20));
    float*  thr     = (float*)(ws + (size_t)(20u << 20));
    int*    tneed   = (int*)  (ws + (size_t)(20u << 20) + (512u << 10));

    hipLaunchKernelGGL(k_pack, dim3(N1 / 64, NB), dim3(256), 0, stream,
                       xyz1, feat1, flow, feat1T, aux4, flow4);
    hipLaunchKernelGGL(k_knn5, dim3(NQ / 512, SPLIT1), dim3(256), 0, stream,
                       xyz1, xyz2, partd);
    hipLaunchKernelGGL(k_thr, dim3(NQ / 256), dim3(256), 0, stream,
                       partd, thr, tneed);
    hipLaunchKernelGGL(k_sel4, dim3(NQ / 8), dim3(256), 0, stream,
                       xyz1, xyz2, thr, tneed, knn_idx);
    hipLaunchKernelGGL(k_mlp5, dim3(NQ / 32), dim3(256), 0, stream,
                       feat1T, aux4, flow4, knn_idx, xyz2, W1, b1, W2, b2, out);
}